// Round 2
// baseline (209.474 us; speedup 1.0000x reference)
//
#include <hip/hip_runtime.h>

// YOLO-v1 loss, S=14, B=2, C=20, NCH=30, Nb=4096.
// R3 (retry; previous run was a container-acquisition failure, not a kernel error):
// inputs (192.7 MB) are L3-resident -> LDS staging + vmcnt(0) barrier drain
// was the bottleneck (2 blocks/CU, 60KB LDS). Direct per-cell float2 loads,
// no LDS staging, ~16 waves/CU. Wave sweeps a contiguous 7.7KB window so all
// cache lines are fully consumed.

#define S_GRID 14
#define NB 4096
#define NCELL (NB * S_GRID * S_GRID)   // 802816 = 3136 * 256
#define NCH 30
#define CELLS_PER_BLOCK 256
#define NBLOCKS (NCELL / CELLS_PER_BLOCK)   // 3136

__global__ __launch_bounds__(256, 4) void yolo_loss_partial(
    const float* __restrict__ pred, const float* __restrict__ target,
    float* __restrict__ partial)
{
    const int cell = blockIdx.x * CELLS_PER_BLOCK + threadIdx.x;  // exact grid
    const float2* __restrict__ p2 = (const float2*)(pred + (size_t)cell * NCH);
    const float2* __restrict__ t2 = (const float2*)(target + (size_t)cell * NCH);

    // Box channels 0..9 (float2 indices 0..4), 8B-aligned (cell*120 % 8 == 0).
    float p[10], t[10];
#pragma unroll
    for (int i = 0; i < 5; ++i) {
        float2 a = p2[i]; p[2 * i] = a.x; p[2 * i + 1] = a.y;
        float2 b = t2[i]; t[2 * i] = b.x; t[2 * i + 1] = b.y;
    }

    const float t4 = t[4];
    const bool obj = (t4 > 0.0f);

    // no-object confidence loss over both box slots
    float dn0 = p[4] - t[4];
    float dn1 = p[9] - t[9];
    float noobj_l = (t4 == 0.0f) ? (dn0 * dn0 + dn1 * dn1) : 0.0f;

    // target box (slot 0) corners
    const float invS = 1.0f / 14.0f;
    float tcx = t[0] * invS, tcy = t[1] * invS;
    float tx1 = tcx - 0.5f * t[2], ty1 = tcy - 0.5f * t[3];
    float tx2 = tcx + 0.5f * t[2], ty2 = tcy + 0.5f * t[3];
    float area_t = (tx2 - tx1) * (ty2 - ty1);

    float iou[2];
#pragma unroll
    for (int b = 0; b < 2; ++b) {
        const float* pb = p + 5 * b;
        float cx = pb[0] * invS, cy = pb[1] * invS;
        float x1 = cx - 0.5f * pb[2], y1 = cy - 0.5f * pb[3];
        float x2 = cx + 0.5f * pb[2], y2 = cy + 0.5f * pb[3];
        float lx = fmaxf(x1, tx1), ly = fmaxf(y1, ty1);
        float rx = fminf(x2, tx2), ry = fminf(y2, ty2);
        float wx = fmaxf(rx - lx, 0.0f), wy = fmaxf(ry - ly, 0.0f);
        float inter = wx * wy;
        float area_p = (x2 - x1) * (y2 - y1);
        iou[b] = inter / (area_p + area_t - inter);
    }

    // jnp.argmax picks first max -> box 1 only on strict >
    int r = (iou[1] > iou[0]) ? 1 : 0;
    float max_iou = fmaxf(iou[0], iou[1]);

    // class loss: channels 10..29 = float2 indices 5..14, accumulate streaming
    float lcls = 0.0f;
#pragma unroll
    for (int i = 5; i < 15; ++i) {
        float2 a = p2[i];
        float2 b = t2[i];
        float d0 = a.x - b.x, d1 = a.y - b.y;
        lcls += d0 * d0 + d1 * d1;
    }

    float obj_l = 0.0f;
    if (obj) {
        const float* pr = p + 5 * r;
        const float* tr = t + 5 * r;
        float dx = pr[0] - tr[0], dy = pr[1] - tr[1];
        float lxy = dx * dx + dy * dy;
        float dw = sqrtf(pr[2]) - sqrtf(tr[2]);
        float dh = sqrtf(pr[3]) - sqrtf(tr[3]);
        float lwh = dw * dw + dh * dh;
        float dob = pr[4] - max_iou;
        float lob = dob * dob;
        obj_l = 5.0f * (lxy + lwh) + lob + lcls;
    }
    float loss = obj_l + 0.5f * noobj_l;

    // wave (64-lane) shuffle reduce, then cross-wave via LDS
    float v = loss;
#pragma unroll
    for (int off = 32; off > 0; off >>= 1)
        v += __shfl_down(v, off, 64);

    __shared__ float red[4];
    const int lane = threadIdx.x & 63;
    const int wid = threadIdx.x >> 6;
    if (lane == 0) red[wid] = v;
    __syncthreads();
    if (threadIdx.x == 0)
        partial[blockIdx.x] = red[0] + red[1] + red[2] + red[3];
}

__global__ __launch_bounds__(256) void yolo_loss_finalize(
    const float* __restrict__ partial, float* __restrict__ out)
{
    double s = 0.0;
    for (int i = threadIdx.x; i < NBLOCKS; i += 256)
        s += (double)partial[i];

    __shared__ double sh[256];
    sh[threadIdx.x] = s;
    __syncthreads();
#pragma unroll
    for (int step = 128; step > 0; step >>= 1) {
        if (threadIdx.x < step) sh[threadIdx.x] += sh[threadIdx.x + step];
        __syncthreads();
    }
    if (threadIdx.x == 0)
        out[0] = (float)(sh[0] / (double)NB);
}

extern "C" void kernel_launch(void* const* d_in, const int* in_sizes, int n_in,
                              void* d_out, int out_size, void* d_ws, size_t ws_size,
                              hipStream_t stream) {
    const float* pred = (const float*)d_in[0];
    const float* target = (const float*)d_in[1];
    float* out = (float*)d_out;
    float* partial = (float*)d_ws;   // NBLOCKS floats = 12.5 KB scratch

    yolo_loss_partial<<<NBLOCKS, 256, 0, stream>>>(pred, target, partial);
    yolo_loss_finalize<<<1, 256, 0, stream>>>(partial, out);
}

// Round 3
// 209.090 us; speedup vs baseline: 1.0018x; 1.0018x over previous
//
#include <hip/hip_runtime.h>

// YOLO-v1 loss, S=14, B=2, C=20, NCH=30, Nb=4096.
// R4: R3 was latency-bound (VGPR=36 -> compiler serialized the 30x dwordx2
// load stream; VALUBusy 9.5%, HBM 1.45 TB/s on the ~107MB that misses L3).
// Fix: 2 cells/thread -> 240B/thread = 15x float4 (16B-aligned only at the
// cell-PAIR granularity), full 120-float register working set so all loads
// stay in flight. launch_bounds(256,2) to allow ~140 VGPR without spill.

#define S_GRID 14
#define NB 4096
#define NCELL (NB * S_GRID * S_GRID)   // 802816
#define NCH 30
#define NPAIR (NCELL / 2)              // 401408
#define PAIRS_PER_BLOCK 256
#define NBLOCKS (NPAIR / PAIRS_PER_BLOCK)   // 1568

__device__ __forceinline__ float cell_loss(const float* __restrict__ p,
                                           const float* __restrict__ t)
{
    const float t4 = t[4];
    const bool obj = (t4 > 0.0f);

    // no-object confidence loss over both box slots
    float dn0 = p[4] - t[4];
    float dn1 = p[9] - t[9];
    float noobj_l = (t4 == 0.0f) ? (dn0 * dn0 + dn1 * dn1) : 0.0f;

    // target box (slot 0) corners
    const float invS = 1.0f / 14.0f;
    float tcx = t[0] * invS, tcy = t[1] * invS;
    float tx1 = tcx - 0.5f * t[2], ty1 = tcy - 0.5f * t[3];
    float tx2 = tcx + 0.5f * t[2], ty2 = tcy + 0.5f * t[3];
    float area_t = (tx2 - tx1) * (ty2 - ty1);

    float iou[2];
#pragma unroll
    for (int b = 0; b < 2; ++b) {
        float cx = p[5 * b + 0] * invS, cy = p[5 * b + 1] * invS;
        float x1 = cx - 0.5f * p[5 * b + 2], y1 = cy - 0.5f * p[5 * b + 3];
        float x2 = cx + 0.5f * p[5 * b + 2], y2 = cy + 0.5f * p[5 * b + 3];
        float lx = fmaxf(x1, tx1), ly = fmaxf(y1, ty1);
        float rx = fminf(x2, tx2), ry = fminf(y2, ty2);
        float wx = fmaxf(rx - lx, 0.0f), wy = fmaxf(ry - ly, 0.0f);
        float inter = wx * wy;
        float area_p = (x2 - x1) * (y2 - y1);
        iou[b] = inter / (area_p + area_t - inter);
    }

    // jnp.argmax picks first max -> box 1 only on strict >
    const bool r = (iou[1] > iou[0]);
    float max_iou = fmaxf(iou[0], iou[1]);

    // responsible-box values via explicit selects (no runtime indexing)
    float pr0 = r ? p[5] : p[0], tr0 = r ? t[5] : t[0];
    float pr1 = r ? p[6] : p[1], tr1 = r ? t[6] : t[1];
    float pr2 = r ? p[7] : p[2], tr2 = r ? t[7] : t[2];
    float pr3 = r ? p[8] : p[3], tr3 = r ? t[8] : t[3];
    float pr4 = r ? p[9] : p[4];

    // class loss (streams; only summed when obj)
    float lcls = 0.0f;
#pragma unroll
    for (int c = 10; c < 30; ++c) {
        float d = p[c] - t[c];
        lcls += d * d;
    }

    float obj_l = 0.0f;
    if (obj) {
        float dx = pr0 - tr0, dy = pr1 - tr1;
        float lxy = dx * dx + dy * dy;
        float dw = sqrtf(pr2) - sqrtf(tr2);
        float dh = sqrtf(pr3) - sqrtf(tr3);
        float lwh = dw * dw + dh * dh;
        float dob = pr4 - max_iou;
        float lob = dob * dob;
        obj_l = 5.0f * (lxy + lwh) + lob + lcls;
    }
    return obj_l + 0.5f * noobj_l;
}

__global__ __launch_bounds__(256, 2) void yolo_loss_partial(
    const float* __restrict__ pred, const float* __restrict__ target,
    float* __restrict__ partial)
{
    const int cp = blockIdx.x * PAIRS_PER_BLOCK + threadIdx.x;  // exact grid
    const float4* __restrict__ pv = (const float4*)(pred + (size_t)cp * 2 * NCH);
    const float4* __restrict__ tv = (const float4*)(target + (size_t)cp * 2 * NCH);

    // 240B per thread, 16B-aligned: 15 dwordx4 per tensor, all in flight.
    float pf[60], tf[60];
#pragma unroll
    for (int i = 0; i < 15; ++i) {
        float4 a = pv[i];
        pf[4 * i + 0] = a.x; pf[4 * i + 1] = a.y;
        pf[4 * i + 2] = a.z; pf[4 * i + 3] = a.w;
    }
#pragma unroll
    for (int i = 0; i < 15; ++i) {
        float4 b = tv[i];
        tf[4 * i + 0] = b.x; tf[4 * i + 1] = b.y;
        tf[4 * i + 2] = b.z; tf[4 * i + 3] = b.w;
    }

    float loss = cell_loss(pf, tf) + cell_loss(pf + NCH, tf + NCH);

    // wave (64-lane) shuffle reduce, then cross-wave via LDS
    float v = loss;
#pragma unroll
    for (int off = 32; off > 0; off >>= 1)
        v += __shfl_down(v, off, 64);

    __shared__ float red[4];
    const int lane = threadIdx.x & 63;
    const int wid = threadIdx.x >> 6;
    if (lane == 0) red[wid] = v;
    __syncthreads();
    if (threadIdx.x == 0)
        partial[blockIdx.x] = red[0] + red[1] + red[2] + red[3];
}

__global__ __launch_bounds__(256) void yolo_loss_finalize(
    const float* __restrict__ partial, float* __restrict__ out)
{
    double s = 0.0;
    for (int i = threadIdx.x; i < NBLOCKS; i += 256)
        s += (double)partial[i];

    __shared__ double sh[256];
    sh[threadIdx.x] = s;
    __syncthreads();
#pragma unroll
    for (int step = 128; step > 0; step >>= 1) {
        if (threadIdx.x < step) sh[threadIdx.x] += sh[threadIdx.x + step];
        __syncthreads();
    }
    if (threadIdx.x == 0)
        out[0] = (float)(sh[0] / (double)NB);
}

extern "C" void kernel_launch(void* const* d_in, const int* in_sizes, int n_in,
                              void* d_out, int out_size, void* d_ws, size_t ws_size,
                              hipStream_t stream) {
    const float* pred = (const float*)d_in[0];
    const float* target = (const float*)d_in[1];
    float* out = (float*)d_out;
    float* partial = (float*)d_ws;   // NBLOCKS floats = 6.1 KB scratch

    yolo_loss_partial<<<NBLOCKS, 256, 0, stream>>>(pred, target, partial);
    yolo_loss_finalize<<<1, 256, 0, stream>>>(partial, out);
}

// Round 4
// 205.315 us; speedup vs baseline: 1.0203x; 1.0184x over previous
//
#include <hip/hip_runtime.h>

// YOLO-v1 loss, S=14, B=2, C=20, NCH=30, Nb=4096.
// R5: R3/R4 both flat at ~75us / 1.3 TB/s across a 3x occupancy and 2x
// load-width change -> the binding constraint is loads-in-flight per wave
// (VGPR 36/76: compiler emitted load->use chains, ~2 outstanding).
// Fix: pin all 15 float2 per tensor live via empty asm "+v" ties so the
// compiler must issue all 30 loads back-to-back, one counted waitcnt, then
// compute. ~15 KB in flight/wave x ~24 waves/CU (grid-limited).

#define S_GRID 14
#define NB 4096
#define NCELL (NB * S_GRID * S_GRID)   // 802816 = 3136 * 256
#define NCH 30
#define CELLS_PER_BLOCK 256
#define NBLOCKS (NCELL / CELLS_PER_BLOCK)   // 3136

__global__ __launch_bounds__(256) void yolo_loss_partial(
    const float* __restrict__ pred, const float* __restrict__ target,
    float* __restrict__ partial)
{
    const int cell = blockIdx.x * CELLS_PER_BLOCK + threadIdx.x;  // exact grid
    const float2* __restrict__ p2 = (const float2*)(pred + (size_t)cell * NCH);
    const float2* __restrict__ t2 = (const float2*)(target + (size_t)cell * NCH);

    // Issue all 30 dwordx2 loads; first use of every value is the asm tie
    // below, so the scheduler cannot interleave consumption with the loads.
    float2 P0 = p2[0], P1 = p2[1], P2 = p2[2], P3 = p2[3], P4 = p2[4];
    float2 P5 = p2[5], P6 = p2[6], P7 = p2[7], P8 = p2[8], P9 = p2[9];
    float2 P10 = p2[10], P11 = p2[11], P12 = p2[12], P13 = p2[13], P14 = p2[14];
    float2 T0 = t2[0], T1 = t2[1], T2 = t2[2], T3 = t2[3], T4 = t2[4];
    float2 T5 = t2[5], T6 = t2[6], T7 = t2[7], T8 = t2[8], T9 = t2[9];
    float2 T10 = t2[10], T11 = t2[11], T12 = t2[12], T13 = t2[13], T14 = t2[14];

    asm volatile("" : "+v"(P0), "+v"(P1), "+v"(P2), "+v"(P3), "+v"(P4),
                      "+v"(P5), "+v"(P6), "+v"(P7), "+v"(P8), "+v"(P9),
                      "+v"(P10), "+v"(P11), "+v"(P12), "+v"(P13), "+v"(P14));
    asm volatile("" : "+v"(T0), "+v"(T1), "+v"(T2), "+v"(T3), "+v"(T4),
                      "+v"(T5), "+v"(T6), "+v"(T7), "+v"(T8), "+v"(T9),
                      "+v"(T10), "+v"(T11), "+v"(T12), "+v"(T13), "+v"(T14));

    // Unpack (all static indices -> registers).
    float p[10], t[10];
    p[0] = P0.x; p[1] = P0.y; p[2] = P1.x; p[3] = P1.y; p[4] = P2.x;
    p[5] = P2.y; p[6] = P3.x; p[7] = P3.y; p[8] = P4.x; p[9] = P4.y;
    t[0] = T0.x; t[1] = T0.y; t[2] = T1.x; t[3] = T1.y; t[4] = T2.x;
    t[5] = T2.y; t[6] = T3.x; t[7] = T3.y; t[8] = T4.x; t[9] = T4.y;

    const float t4 = t[4];
    const bool obj = (t4 > 0.0f);

    // no-object confidence loss over both box slots
    float dn0 = p[4] - t[4];
    float dn1 = p[9] - t[9];
    float noobj_l = (t4 == 0.0f) ? (dn0 * dn0 + dn1 * dn1) : 0.0f;

    // target box (slot 0) corners
    const float invS = 1.0f / 14.0f;
    float tcx = t[0] * invS, tcy = t[1] * invS;
    float tx1 = tcx - 0.5f * t[2], ty1 = tcy - 0.5f * t[3];
    float tx2 = tcx + 0.5f * t[2], ty2 = tcy + 0.5f * t[3];
    float area_t = (tx2 - tx1) * (ty2 - ty1);

    float iou[2];
#pragma unroll
    for (int b = 0; b < 2; ++b) {
        const float* pb = p + 5 * b;
        float cx = pb[0] * invS, cy = pb[1] * invS;
        float x1 = cx - 0.5f * pb[2], y1 = cy - 0.5f * pb[3];
        float x2 = cx + 0.5f * pb[2], y2 = cy + 0.5f * pb[3];
        float lx = fmaxf(x1, tx1), ly = fmaxf(y1, ty1);
        float rx = fminf(x2, tx2), ry = fminf(y2, ty2);
        float wx = fmaxf(rx - lx, 0.0f), wy = fmaxf(ry - ly, 0.0f);
        float inter = wx * wy;
        float area_p = (x2 - x1) * (y2 - y1);
        iou[b] = inter / (area_p + area_t - inter);
    }

    // jnp.argmax picks first max -> box 1 only on strict >
    const bool r = (iou[1] > iou[0]);
    float max_iou = fmaxf(iou[0], iou[1]);

    // responsible-box values via explicit selects
    float pr0 = r ? p[5] : p[0], tr0 = r ? t[5] : t[0];
    float pr1 = r ? p[6] : p[1], tr1 = r ? t[6] : t[1];
    float pr2 = r ? p[7] : p[2], tr2 = r ? t[7] : t[2];
    float pr3 = r ? p[8] : p[3], tr3 = r ? t[8] : t[3];
    float pr4 = r ? p[9] : p[4];

    // class loss: channels 10..29 = float2 pairs P5..P14 / T5..T14
    float lcls = 0.0f;
    {
        float d;
        d = P5.x - T5.x;   lcls += d * d;  d = P5.y - T5.y;   lcls += d * d;
        d = P6.x - T6.x;   lcls += d * d;  d = P6.y - T6.y;   lcls += d * d;
        d = P7.x - T7.x;   lcls += d * d;  d = P7.y - T7.y;   lcls += d * d;
        d = P8.x - T8.x;   lcls += d * d;  d = P8.y - T8.y;   lcls += d * d;
        d = P9.x - T9.x;   lcls += d * d;  d = P9.y - T9.y;   lcls += d * d;
        d = P10.x - T10.x; lcls += d * d;  d = P10.y - T10.y; lcls += d * d;
        d = P11.x - T11.x; lcls += d * d;  d = P11.y - T11.y; lcls += d * d;
        d = P12.x - T12.x; lcls += d * d;  d = P12.y - T12.y; lcls += d * d;
        d = P13.x - T13.x; lcls += d * d;  d = P13.y - T13.y; lcls += d * d;
        d = P14.x - T14.x; lcls += d * d;  d = P14.y - T14.y; lcls += d * d;
    }

    float obj_l = 0.0f;
    if (obj) {
        float dx = pr0 - tr0, dy = pr1 - tr1;
        float lxy = dx * dx + dy * dy;
        float dw = sqrtf(pr2) - sqrtf(tr2);
        float dh = sqrtf(pr3) - sqrtf(tr3);
        float lwh = dw * dw + dh * dh;
        float dob = pr4 - max_iou;
        float lob = dob * dob;
        obj_l = 5.0f * (lxy + lwh) + lob + lcls;
    }
    float loss = obj_l + 0.5f * noobj_l;

    // wave (64-lane) shuffle reduce, then cross-wave via LDS
    float v = loss;
#pragma unroll
    for (int off = 32; off > 0; off >>= 1)
        v += __shfl_down(v, off, 64);

    __shared__ float red[4];
    const int lane = threadIdx.x & 63;
    const int wid = threadIdx.x >> 6;
    if (lane == 0) red[wid] = v;
    __syncthreads();
    if (threadIdx.x == 0)
        partial[blockIdx.x] = red[0] + red[1] + red[2] + red[3];
}

__global__ __launch_bounds__(256) void yolo_loss_finalize(
    const float* __restrict__ partial, float* __restrict__ out)
{
    double s = 0.0;
    for (int i = threadIdx.x; i < NBLOCKS; i += 256)
        s += (double)partial[i];

    __shared__ double sh[256];
    sh[threadIdx.x] = s;
    __syncthreads();
#pragma unroll
    for (int step = 128; step > 0; step >>= 1) {
        if (threadIdx.x < step) sh[threadIdx.x] += sh[threadIdx.x + step];
        __syncthreads();
    }
    if (threadIdx.x == 0)
        out[0] = (float)(sh[0] / (double)NB);
}

extern "C" void kernel_launch(void* const* d_in, const int* in_sizes, int n_in,
                              void* d_out, int out_size, void* d_ws, size_t ws_size,
                              hipStream_t stream) {
    const float* pred = (const float*)d_in[0];
    const float* target = (const float*)d_in[1];
    float* out = (float*)d_out;
    float* partial = (float*)d_ws;   // NBLOCKS floats = 12.5 KB scratch

    yolo_loss_partial<<<NBLOCKS, 256, 0, stream>>>(pred, target, partial);
    yolo_loss_finalize<<<1, 256, 0, stream>>>(partial, out);
}